// Round 15
// baseline (320.671 us; speedup 1.0000x reference)
//
#include <hip/hip_runtime.h>
#include <math.h>

#define B_ 4
#define T_ 2048
#define D_ 512
#define H_ 8
#define DH_ 64
#define BT_ 8192
#define FF_ 2048
#define EPS_ 1e-5f
#define SCALE_ 0.04419417382415922f   // 512^-0.5
#define SC2_ 0.06375861151f           // SCALE_ * log2(e)
#define NEGINF_ -1e30f

typedef short b16x8 __attribute__((ext_vector_type(8)));
typedef short b16x4 __attribute__((ext_vector_type(4)));
typedef float f32x4 __attribute__((ext_vector_type(4)));

#define MFMA16(a, b, c) __builtin_amdgcn_mfma_f32_16x16x32_bf16(a, b, c, 0, 0, 0)
#define MFMA16K16(a, b, c) __builtin_amdgcn_mfma_f32_16x16x16bf16_1k(a, b, c, 0, 0, 0)

#define GLL16(gp, lp) \
    __builtin_amdgcn_global_load_lds((const __attribute__((address_space(1))) void*)(gp), \
                                     (__attribute__((address_space(3))) void*)(lp), 16, 0, 0)

#if __has_builtin(__builtin_amdgcn_exp2f)
#define EXP2F(x) __builtin_amdgcn_exp2f(x)
#else
#define EXP2F(x) exp2f(x)
#endif

// fp32 -> bf16 RNE (finite inputs)
static __device__ inline short f2bf(float f) {
    unsigned int u = __builtin_bit_cast(unsigned int, f);
    unsigned int r = (u + 0x7fffu + ((u >> 16) & 1u)) >> 16;
    return (short)r;
}
// fp32 -> bf16 truncation (1 VALU op; used for P where bias is negligible)
static __device__ inline short f2bf_trunc(float f) {
    return (short)(__builtin_bit_cast(unsigned int, f) >> 16);
}
// bf16 -> fp32
static __device__ inline float bf2f(short s) {
    return __builtin_bit_cast(float, ((unsigned int)(unsigned short)s) << 16);
}

// ---------------------------------------------------------------------------
// LayerNorm: 256 threads = 4 waves, one row per wave (4 rows/block).
// ---------------------------------------------------------------------------
__global__ __launch_bounds__(256) void ln_kernel(const float* __restrict__ X,
        const float* __restrict__ G, const float* __restrict__ Bb,
        short* __restrict__ Y)
{
    int wave = threadIdx.x >> 6, t = threadIdx.x & 63;
    int row = blockIdx.x * 4 + wave;
    const float* xr = X + (size_t)row * D_;
    float4 v0 = *(const float4*)(xr + t * 4);
    float4 v1 = *(const float4*)(xr + 256 + t * 4);
    float sum = v0.x + v0.y + v0.z + v0.w + v1.x + v1.y + v1.z + v1.w;
    float ssq = v0.x*v0.x + v0.y*v0.y + v0.z*v0.z + v0.w*v0.w
              + v1.x*v1.x + v1.y*v1.y + v1.z*v1.z + v1.w*v1.w;
    #pragma unroll
    for (int off = 32; off > 0; off >>= 1) {
        sum += __shfl_down(sum, off);
        ssq += __shfl_down(ssq, off);
    }
    sum = __shfl(sum, 0);
    ssq = __shfl(ssq, 0);
    float mean = sum * (1.0f / D_);
    float var  = ssq * (1.0f / D_) - mean * mean;
    float rstd = rsqrtf(var + EPS_);

    float4 g0 = *(const float4*)(G + t * 4);
    float4 g1 = *(const float4*)(G + 256 + t * 4);
    float4 b0 = *(const float4*)(Bb + t * 4);
    float4 b1 = *(const float4*)(Bb + 256 + t * 4);
    short4 o0, o1;
    o0.x = f2bf((v0.x - mean) * rstd * g0.x + b0.x);
    o0.y = f2bf((v0.y - mean) * rstd * g0.y + b0.y);
    o0.z = f2bf((v0.z - mean) * rstd * g0.z + b0.z);
    o0.w = f2bf((v0.w - mean) * rstd * g0.w + b0.w);
    o1.x = f2bf((v1.x - mean) * rstd * g1.x + b1.x);
    o1.y = f2bf((v1.y - mean) * rstd * g1.y + b1.y);
    o1.z = f2bf((v1.z - mean) * rstd * g1.z + b1.z);
    o1.w = f2bf((v1.w - mean) * rstd * g1.w + b1.w);
    short* yr = Y + (size_t)row * D_;
    *(short4*)(yr + t * 4)       = o0;
    *(short4*)(yr + 256 + t * 4) = o1;
}

// ---------------------------------------------------------------------------
// All weight transposes fused into one launch. 3072 tiles of 32x32.
// ---------------------------------------------------------------------------
__global__ __launch_bounds__(256) void prep_kernel(
        const float* __restrict__ Wq, const float* __restrict__ Wk,
        const float* __restrict__ Wv, const float* __restrict__ Wp,
        const float* __restrict__ W1, const float* __restrict__ W2,
        short* __restrict__ wqkv, short* __restrict__ wpt,
        short* __restrict__ w1t, short* __restrict__ w2t)
{
    __shared__ float tile[32][33];
    int idx = blockIdx.x;
    const float* src; short* dst; int R, C, tx0, ty0;
    if (idx < 768) {            // Wq/Wk/Wv: per head [512][64] -> [64][512]
        int w = idx >> 8, rem = idx & 255;
        int hh = rem >> 5, t = rem & 31;
        const float* base = (w == 0) ? Wq : ((w == 1) ? Wk : Wv);
        src = base + hh * (D_ * DH_);
        dst = wqkv + w * (512 * 512) + hh * (DH_ * D_);
        R = 512; C = 64; tx0 = (t & 1) * 32; ty0 = (t >> 1) * 32;
    } else if (idx < 1024) {    // Wproj [512][512]
        int t = idx - 768;
        src = Wp; dst = wpt; R = 512; C = 512;
        tx0 = (t & 15) * 32; ty0 = (t >> 4) * 32;
    } else if (idx < 2048) {    // W1 [512][2048] -> [2048][512]
        int t = idx - 1024;
        src = W1; dst = w1t; R = 512; C = 2048;
        tx0 = (t & 63) * 32; ty0 = (t >> 6) * 32;
    } else {                    // W2 [2048][512] -> [512][2048]
        int t = idx - 2048;
        src = W2; dst = w2t; R = 2048; C = 512;
        tx0 = (t & 15) * 32; ty0 = (t >> 4) * 32;
    }
    int tx = threadIdx.x, ty = threadIdx.y;
    #pragma unroll
    for (int i = 0; i < 32; i += 8)
        tile[ty + i][tx] = src[(size_t)(ty0 + ty + i) * C + tx0 + tx];
    __syncthreads();
    #pragma unroll
    for (int i = 0; i < 32; i += 8)
        dst[(size_t)(tx0 + ty + i) * R + ty0 + tx] = f2bf(tile[tx][ty + i]);
}

// ---------------------------------------------------------------------------
// WAVE-AUTONOMOUS bf16 MFMA GEMM: one 64-thread block = one wave = one 64x64
// C-tile. Wave-private dbuf LDS (16 KB -> 10 blocks/CU). NO __syncthreads in
// the K-loop: the GLL->ds_read dependency is the wave's own vmcnt wait, so
// waves never collectively stall on a barrier drain (the R8-R14 counters
// showed all barrier'd GEMM variants latency-bound with all pipes idle).
// Iter order: ds_read frags(buf) [vmcnt wait covers LAST iter's prefetch] ->
// issue GLL prefetch(buf^1) -> 16 MFMA. Staging layout identical to the
// verified conflict-free mm64 swizzle: inst r stages rows r*16+(lane>>2),
// chunk lane&3 holds global seg (lane&3)^((row>>1)&3).
// grid = (M/64, N/64), gridX % 8 == 0 -> XCD-pinned A rows (L2-hot).
// ---------------------------------------------------------------------------
__global__ __launch_bounds__(64) void mmw_kernel(const short* __restrict__ A,
        const short* __restrict__ Bt, void* __restrict__ C,
        const float* __restrict__ bias, const float* __restrict__ resid,
        int M, int N, int K, int relu, int out_bf16)
{
    __shared__ short As[2][64 * 32];
    __shared__ short Bs[2][64 * 32];
    const int lane = threadIdx.x;
    const int quad = lane >> 4, l15 = lane & 15;
    const int m0 = blockIdx.x * 64, n0 = blockIdx.y * 64;
    const int srow = lane >> 2;                 // staging row within 16-row group
    const int schunk = lane & 3;                // staging chunk slot

#define STAGEW(bufi, kk) \
    { \
        _Pragma("unroll") \
        for (int r = 0; r < 4; ++r) { \
            int row = r * 16 + srow; \
            int seg = schunk ^ ((row >> 1) & 3); \
            GLL16(A + (size_t)(m0 + row) * K + (kk) + seg * 8, \
                  As[bufi] + r * 512); \
            GLL16(Bt + (size_t)(n0 + row) * K + (kk) + seg * 8, \
                  Bs[bufi] + r * 512); \
        } \
    }

    f32x4 acc[4][4];
    #pragma unroll
    for (int i = 0; i < 4; ++i)
        #pragma unroll
        for (int j = 0; j < 4; ++j)
            acc[i][j] = (f32x4){0.f, 0.f, 0.f, 0.f};

    STAGEW(0, 0);
    int buf = 0;
    for (int k0 = 0; k0 < K; k0 += 32) {
        // frag reads: compiler inserts s_waitcnt vmcnt(0) here, which waits
        // exactly on the prefetch issued last iteration (wave-private queue).
        b16x8 af[4], bf[4];
        #pragma unroll
        for (int i = 0; i < 4; ++i) {
            int row = i * 16 + l15;
            int c = quad ^ ((row >> 1) & 3);
            af[i] = *(const b16x8*)(As[buf] + row * 32 + c * 8);
            bf[i] = *(const b16x8*)(Bs[buf] + row * 32 + c * 8);
        }
        if (k0 + 32 < K) STAGEW(buf ^ 1, k0 + 32);
        #pragma unroll
        for (int i = 0; i < 4; ++i)
            #pragma unroll
            for (int j = 0; j < 4; ++j)
                acc[i][j] = MFMA16(af[i], bf[j], acc[i][j]);
        buf ^= 1;
    }
#undef STAGEW

    #pragma unroll
    for (int i = 0; i < 4; ++i) {
        #pragma unroll
        for (int r = 0; r < 4; ++r) {
            size_t row = (size_t)(m0 + i * 16 + quad * 4 + r);
            #pragma unroll
            for (int j = 0; j < 4; ++j) {
                int col = n0 + j * 16 + l15;
                float v = acc[i][j][r];
                if (bias)  v += bias[col];
                if (resid) v += resid[row * N + col];
                if (relu)  v = fmaxf(v, 0.0f);
                if (out_bf16) ((short*)C)[row * N + col] = f2bf(v);
                else          ((float*)C)[row * N + col] = v;
            }
        }
    }
}

// ---------------------------------------------------------------------------
// Flash attention, S^T formulation, SPLIT-K x2, STATIC-MAX softmax (m == 0):
// LN-normalized inputs bound |S*SC2| << fp32 exp2 range, so no running max,
// no alpha rescale, and the split combine is pure l-weighting.
// grid (32 bh, 32 qt, 2 split). 25.6 KB LDS, 6 blocks/CU.
// ---------------------------------------------------------------------------
__global__ __launch_bounds__(256) void attn_kernel(const short* __restrict__ qkv,
        short* __restrict__ Opart, float* __restrict__ Ml)
{
    __shared__ short Qs[64 * 72];   // [0..64*64): swizzled Q; epilogue: stride-72 repack
    __shared__ short Ks[64 * 64];   // [tok][dh], swizzled
    __shared__ short Vt[64 * 64];   // [dh][tok], granule-swizzled, stride 64

    const int tid = threadIdx.x;
    const int wave = tid >> 6, lane = tid & 63;
    const int quad = lane >> 4, l15 = lane & 15;
    const int bh = blockIdx.x;
    const int qi = 31 - (int)blockIdx.y;
    const int split = blockIdx.z;
    const int b = bh >> 3, h = bh & 7;
    const size_t tok0 = (size_t)b * T_;
    const int qrow_rel = wave * 16 + l15;
    const int half = (qi + 1) >> 1;
    const int klo = split ? half : 0;
    const int khi = split ? qi + 1 : half;
    const int pidx = split * 1024 + bh * 32 + qi;
    short* Op = Opart + (size_t)pidx * 4096;
    float* mlp = Ml + (size_t)pidx * 64;

    if (klo >= khi) {               // empty split (qi==0, split==0)
        for (int i = tid; i < 2048; i += 256) ((int*)Op)[i] = 0;
        if (tid < 64) mlp[tid] = 0.0f;
        return;
    }

    // stage Q tile (swizzled)
    #pragma unroll
    for (int r = 0; r < 2; ++r) {
        int c = r * 256 + tid;
        int tk = c >> 3;
        int seg = (c & 7) ^ (tk & 7);
        GLL16(qkv + (tok0 + qi * 64 + tk) * 1536 + h * 64 + seg * 8,
              Qs + (size_t)(r * 256 + wave * 64) * 8);
    }

    float lrow = 0.0f;
    f32x4 ot[4];   // O^T: row=dh=dt*16+quad*4+rr, col=qrow=l15
    #pragma unroll
    for (int dt = 0; dt < 4; ++dt) ot[dt] = (f32x4){0.f, 0.f, 0.f, 0.f};

    b16x8 qf[2];

    for (int kj = klo; kj < khi; ++kj) {
        __syncthreads();   // prev-iter LDS reads done (and Q GLL drained on first)
        // stage K tile (swizzled)
        #pragma unroll
        for (int r = 0; r < 2; ++r) {
            int c = r * 256 + tid;
            int tk = c >> 3;
            int seg = (c & 7) ^ (tk & 7);
            GLL16(qkv + (tok0 + kj * 64 + tk) * 1536 + 512 + h * 64 + seg * 8,
                  Ks + (size_t)(r * 256 + wave * 64) * 8);
        }
        // stage V transposed, granule-swizzled: thread = (s 0..7, tp 0..31)
        {
            int s = tid >> 5, tp = tid & 31;
            const short* g0 = qkv + (tok0 + kj * 64 + tp * 2) * 1536 + 1024 + h * 64 + s * 8;
            b16x8 v0 = *(const b16x8*)g0;
            b16x8 v1 = *(const b16x8*)(g0 + 1536);
            int* vo = (int*)Vt;
            int gg = tp >> 1, hlf = tp & 1;
            #pragma unroll
            for (int e = 0; e < 8; ++e) {
                int row = s * 8 + e;
                unsigned int pk = (unsigned int)(unsigned short)v0[e]
                                | ((unsigned int)(unsigned short)v1[e] << 16);
                vo[row * 32 + ((gg ^ (row & 15)) << 1) + hlf] = pk;
            }
        }
        __syncthreads();

        if (kj == klo) {   // Q fragment (B-operand: n=l15=qrow, k=quad*8+j), hoisted
            #pragma unroll
            for (int kb = 0; kb < 2; ++kb) {
                int row = wave * 16 + l15;
                qf[kb] = *(const b16x8*)(Qs + row * 64 + (((kb * 4 + quad) ^ (row & 7)) * 8));
            }
        }

        // S^T = K Q^T  (A=K-frag, B=Q-frag)
        f32x4 st[4];   // mt token-tiles: token = mt*16+quad*4+r, qrow = l15
        #pragma unroll
        for (int mt = 0; mt < 4; ++mt) st[mt] = (f32x4){0.f, 0.f, 0.f, 0.f};
        #pragma unroll
        for (int mt = 0; mt < 4; ++mt) {
            int trow = mt * 16 + l15;
            #pragma unroll
            for (int kb = 0; kb < 2; ++kb) {
                b16x8 kf = *(const b16x8*)(Ks + trow * 64 + (((kb * 4 + quad) ^ (trow & 7)) * 8));
                st[mt] = MFMA16(kf, qf[kb], st[mt]);
            }
        }

        // causal mask + P = exp2(S*SC2) (no max subtraction)
        const bool diag = (kj == qi);
        float rs = 0.0f;
        b16x4 pf[4];   // P^T fragments: directly in 16x16x16 B-operand layout
        #pragma unroll
        for (int mt = 0; mt < 4; ++mt)
            #pragma unroll
            for (int r = 0; r < 4; ++r) {
                float s = st[mt][r];
                if (diag && (mt * 16 + quad * 4 + r) > qrow_rel) s = NEGINF_;
                float e = EXP2F(s * SC2_);
                rs += e;
                pf[mt][r] = f2bf_trunc(e);
            }
        rs += __shfl_xor(rs, 16);
        rs += __shfl_xor(rs, 32);
        lrow += rs;
        // O^T += V^T P^T  (16x16x16; A=V^T-frag from swizzled Vt, B=P^T in regs)
        #pragma unroll
        for (int dt = 0; dt < 4; ++dt) {
            const short* vrow = Vt + (dt * 16 + l15) * 64;
            #pragma unroll
            for (int kt = 0; kt < 4; ++kt) {
                b16x4 vf = *(const b16x4*)(vrow + (((kt * 4 + quad) ^ l15) << 2));
                ot[dt] = MFMA16K16(vf, pf[kt], ot[dt]);
            }
        }
    }

    // epilogue: normalize, repack via same-wave LDS strip (Qs alias), store
    __syncthreads();   // all waves done reading Ks/Vt AND Qs fragments
    float inv = 1.0f / lrow;
    #pragma unroll
    for (int dt = 0; dt < 4; ++dt) {
        b16x4 o4;
        o4[0] = f2bf(ot[dt][0] * inv);
        o4[1] = f2bf(ot[dt][1] * inv);
        o4[2] = f2bf(ot[dt][2] * inv);
        o4[3] = f2bf(ot[dt][3] * inv);
        *(b16x4*)(Qs + (size_t)qrow_rel * 72 + dt * 16 + quad * 4) = o4;
    }
    // rows tid>>2 land inside this wave's own strip -> DS in-order, no barrier
    {
        int row = tid >> 2, ch = tid & 3;
        b16x8 lo = *(const b16x8*)(Qs + (size_t)row * 72 + ch * 16);
        b16x8 hi = *(const b16x8*)(Qs + (size_t)row * 72 + ch * 16 + 8);
        short* dst = Op + row * 64 + ch * 16;
        *(b16x8*)dst = lo;
        *(b16x8*)(dst + 8) = hi;
    }
    if (quad == 0) mlp[qrow_rel] = lrow;
}

// ---------------------------------------------------------------------------
// Combine the two attn split-K partials: O = (l1*O1 + l2*O2)/(l1+l2).
// grid 1024 (one (bh,qi) per block), 256 threads.
// ---------------------------------------------------------------------------
__global__ __launch_bounds__(256) void attn_combine_kernel(
        const short* __restrict__ Opart, const float* __restrict__ Ml,
        short* __restrict__ Ob)
{
    int pair = blockIdx.x;              // bh*32 + qi
    int bh = pair >> 5, qi = pair & 31;
    int b = bh >> 3, h = bh & 7;
    int tid = threadIdx.x;
    const short* O1 = Opart + (size_t)pair * 4096;
    const short* O2 = Opart + (size_t)(1024 + pair) * 4096;
    const float* ml1 = Ml + (size_t)pair * 64;
    const float* ml2 = Ml + (size_t)(1024 + pair) * 64;
    int ch = tid & 7;                   // 8 shorts per chunk
    #pragma unroll
    for (int it = 0; it < 2; ++it) {
        int row = it * 32 + (tid >> 3);
        float l1 = ml1[row], l2 = ml2[row];
        float inv = 1.0f / (l1 + l2);
        float w1 = l1 * inv, w2 = l2 * inv;
        b16x8 a = *(const b16x8*)(O1 + row * 64 + ch * 8);
        b16x8 c = *(const b16x8*)(O2 + row * 64 + ch * 8);
        b16x8 o;
        #pragma unroll
        for (int e = 0; e < 8; ++e)
            o[e] = f2bf(w1 * bf2f(a[e]) + w2 * bf2f(c[e]));
        short* dst = Ob + ((size_t)(b * T_ + qi * 64 + row)) * 512 + h * 64 + ch * 8;
        *(b16x8*)dst = o;
    }
}

// ---------------------------------------------------------------------------
extern "C" void kernel_launch(void* const* d_in, const int* in_sizes, int n_in,
                              void* d_out, int out_size, void* d_ws, size_t ws_size,
                              hipStream_t stream) {
    (void)in_sizes; (void)n_in; (void)out_size; (void)ws_size;
    const float* x     = (const float*)d_in[0];
    const float* ln_g  = (const float*)d_in[1];
    const float* ln_b  = (const float*)d_in[2];
    const float* Wq    = (const float*)d_in[3];
    const float* Wk    = (const float*)d_in[4];
    const float* Wv    = (const float*)d_in[5];
    const float* Wproj = (const float*)d_in[6];
    const float* bproj = (const float*)d_in[7];
    const float* W1    = (const float*)d_in[8];
    const float* b1    = (const float*)d_in[9];
    const float* W2    = (const float*)d_in[10];
    const float* b2    = (const float*)d_in[11];
    float* out = (float*)d_out;

    char* W = (char*)d_ws;
    short* hbuf  = (short*)(W + 0);                    // 8 MB  (LN out, bf16)
    short* qkvb  = (short*)(W + ((size_t)8  << 20));   // 24 MB [BT][1536]
    short* attno = (short*)(W + ((size_t)32 << 20));   // 8 MB  [BT][512]
    float* x1    = (float*)(W + ((size_t)40 << 20));   // 16 MB
    short* ff1   = (short*)(W + ((size_t)56 << 20));   // 32 MB [BT][2048]
    short* wqkv  = (short*)(W + ((size_t)88 << 20));   // 1.5 MB [1536][512]
    short* wpt   = (short*)(W + ((size_t)90 << 20));   // 0.5 MB [512][512]
    short* w1t   = (short*)(W + ((size_t)91 << 20));   // 2 MB  [2048][512]
    short* w2t   = (short*)(W + ((size_t)93 << 20));   // 2 MB  [512][2048]
    short* Opart = (short*)(W + ((size_t)96 << 20));   // 16 MB [2][1024][64][64] bf16
    float* Ml    = (float*)(W + ((size_t)112 << 20));  // 0.5 MB [2][1024][64] fp32

    // 0. all weight transposes in one launch
    prep_kernel<<<dim3(3072), dim3(32, 8), 0, stream>>>(
        Wq, Wk, Wv, Wproj, W1, W2, wqkv, wpt, w1t, w2t);
    // 1. h = LN(x) -> bf16
    ln_kernel<<<dim3(BT_ / 4), dim3(256), 0, stream>>>(x, ln_g, ln_b, hbuf);
    // 2. qkv = h @ Wqkv  (wave-autonomous 64x64 tiles, 3072 waves)
    mmw_kernel<<<dim3(128, 24), dim3(64), 0, stream>>>(hbuf, wqkv, qkvb,
        nullptr, nullptr, BT_, 1536, D_, 0, 1);
    // 3. attention split-K x2 -> partials, then combine -> attno bf16
    attn_kernel<<<dim3(32, 32, 2), dim3(256), 0, stream>>>(qkvb, Opart, Ml);
    attn_combine_kernel<<<dim3(1024), dim3(256), 0, stream>>>(Opart, Ml, attno);
    // 4. x1 = x + attno @ Wproj + bproj  (fp32)
    mmw_kernel<<<dim3(128, 8), dim3(64), 0, stream>>>(attno, wpt, x1,
        bproj, x, BT_, D_, D_, 0, 0);
    // 5. h2 = LN(x1) -> bf16 (reuse hbuf)
    ln_kernel<<<dim3(BT_ / 4), dim3(256), 0, stream>>>(x1, ln_g, ln_b, hbuf);
    // 6. ff1 = relu(h2 @ W1 + b1)  bf16 (4096 waves)
    mmw_kernel<<<dim3(128, 32), dim3(64), 0, stream>>>(hbuf, w1t, ff1,
        b1, nullptr, BT_, FF_, D_, 1, 1);
    // 7. out = x1 + ff1 @ W2 + b2  (fp32, K=2048 -> 64 wave-private iters)
    mmw_kernel<<<dim3(128, 8), dim3(64), 0, stream>>>(ff1, w2t, out,
        b2, x1, BT_, D_, FF_, 0, 0);
}

// Round 16
// 258.846 us; speedup vs baseline: 1.2388x; 1.2388x over previous
//
#include <hip/hip_runtime.h>
#include <math.h>

#define B_ 4
#define T_ 2048
#define D_ 512
#define H_ 8
#define DH_ 64
#define BT_ 8192
#define FF_ 2048
#define EPS_ 1e-5f
#define SCALE_ 0.04419417382415922f   // 512^-0.5
#define SC2_ 0.06375861151f           // SCALE_ * log2(e)
#define NEGINF_ -1e30f

typedef short b16x8 __attribute__((ext_vector_type(8)));
typedef short b16x4 __attribute__((ext_vector_type(4)));
typedef float f32x4 __attribute__((ext_vector_type(4)));

#define MFMA16(a, b, c) __builtin_amdgcn_mfma_f32_16x16x32_bf16(a, b, c, 0, 0, 0)
#define MFMA16K16(a, b, c) __builtin_amdgcn_mfma_f32_16x16x16bf16_1k(a, b, c, 0, 0, 0)

#define GLL16(gp, lp) \
    __builtin_amdgcn_global_load_lds((const __attribute__((address_space(1))) void*)(gp), \
                                     (__attribute__((address_space(3))) void*)(lp), 16, 0, 0)

#if __has_builtin(__builtin_amdgcn_exp2f)
#define EXP2F(x) __builtin_amdgcn_exp2f(x)
#else
#define EXP2F(x) exp2f(x)
#endif

// fp32 -> bf16 RNE (finite inputs)
static __device__ inline short f2bf(float f) {
    unsigned int u = __builtin_bit_cast(unsigned int, f);
    unsigned int r = (u + 0x7fffu + ((u >> 16) & 1u)) >> 16;
    return (short)r;
}
// fp32 -> bf16 truncation (1 VALU op; used for P where bias is negligible)
static __device__ inline short f2bf_trunc(float f) {
    return (short)(__builtin_bit_cast(unsigned int, f) >> 16);
}
// bf16 -> fp32
static __device__ inline float bf2f(short s) {
    return __builtin_bit_cast(float, ((unsigned int)(unsigned short)s) << 16);
}

// ---------------------------------------------------------------------------
// LayerNorm: 256 threads = 4 waves, one row per wave (4 rows/block).
// ---------------------------------------------------------------------------
__global__ __launch_bounds__(256) void ln_kernel(const float* __restrict__ X,
        const float* __restrict__ G, const float* __restrict__ Bb,
        short* __restrict__ Y)
{
    int wave = threadIdx.x >> 6, t = threadIdx.x & 63;
    int row = blockIdx.x * 4 + wave;
    const float* xr = X + (size_t)row * D_;
    float4 v0 = *(const float4*)(xr + t * 4);
    float4 v1 = *(const float4*)(xr + 256 + t * 4);
    float sum = v0.x + v0.y + v0.z + v0.w + v1.x + v1.y + v1.z + v1.w;
    float ssq = v0.x*v0.x + v0.y*v0.y + v0.z*v0.z + v0.w*v0.w
              + v1.x*v1.x + v1.y*v1.y + v1.z*v1.z + v1.w*v1.w;
    #pragma unroll
    for (int off = 32; off > 0; off >>= 1) {
        sum += __shfl_down(sum, off);
        ssq += __shfl_down(ssq, off);
    }
    sum = __shfl(sum, 0);
    ssq = __shfl(ssq, 0);
    float mean = sum * (1.0f / D_);
    float var  = ssq * (1.0f / D_) - mean * mean;
    float rstd = rsqrtf(var + EPS_);

    float4 g0 = *(const float4*)(G + t * 4);
    float4 g1 = *(const float4*)(G + 256 + t * 4);
    float4 b0 = *(const float4*)(Bb + t * 4);
    float4 b1 = *(const float4*)(Bb + 256 + t * 4);
    short4 o0, o1;
    o0.x = f2bf((v0.x - mean) * rstd * g0.x + b0.x);
    o0.y = f2bf((v0.y - mean) * rstd * g0.y + b0.y);
    o0.z = f2bf((v0.z - mean) * rstd * g0.z + b0.z);
    o0.w = f2bf((v0.w - mean) * rstd * g0.w + b0.w);
    o1.x = f2bf((v1.x - mean) * rstd * g1.x + b1.x);
    o1.y = f2bf((v1.y - mean) * rstd * g1.y + b1.y);
    o1.z = f2bf((v1.z - mean) * rstd * g1.z + b1.z);
    o1.w = f2bf((v1.w - mean) * rstd * g1.w + b1.w);
    short* yr = Y + (size_t)row * D_;
    *(short4*)(yr + t * 4)       = o0;
    *(short4*)(yr + 256 + t * 4) = o1;
}

// ---------------------------------------------------------------------------
// All weight transposes fused into one launch. 3072 tiles of 32x32.
// ---------------------------------------------------------------------------
__global__ __launch_bounds__(256) void prep_kernel(
        const float* __restrict__ Wq, const float* __restrict__ Wk,
        const float* __restrict__ Wv, const float* __restrict__ Wp,
        const float* __restrict__ W1, const float* __restrict__ W2,
        short* __restrict__ wqkv, short* __restrict__ wpt,
        short* __restrict__ w1t, short* __restrict__ w2t)
{
    __shared__ float tile[32][33];
    int idx = blockIdx.x;
    const float* src; short* dst; int R, C, tx0, ty0;
    if (idx < 768) {            // Wq/Wk/Wv: per head [512][64] -> [64][512]
        int w = idx >> 8, rem = idx & 255;
        int hh = rem >> 5, t = rem & 31;
        const float* base = (w == 0) ? Wq : ((w == 1) ? Wk : Wv);
        src = base + hh * (D_ * DH_);
        dst = wqkv + w * (512 * 512) + hh * (DH_ * D_);
        R = 512; C = 64; tx0 = (t & 1) * 32; ty0 = (t >> 1) * 32;
    } else if (idx < 1024) {    // Wproj [512][512]
        int t = idx - 768;
        src = Wp; dst = wpt; R = 512; C = 512;
        tx0 = (t & 15) * 32; ty0 = (t >> 4) * 32;
    } else if (idx < 2048) {    // W1 [512][2048] -> [2048][512]
        int t = idx - 1024;
        src = W1; dst = w1t; R = 512; C = 2048;
        tx0 = (t & 63) * 32; ty0 = (t >> 6) * 32;
    } else {                    // W2 [2048][512] -> [512][2048]
        int t = idx - 2048;
        src = W2; dst = w2t; R = 2048; C = 512;
        tx0 = (t & 15) * 32; ty0 = (t >> 4) * 32;
    }
    int tx = threadIdx.x, ty = threadIdx.y;
    #pragma unroll
    for (int i = 0; i < 32; i += 8)
        tile[ty + i][tx] = src[(size_t)(ty0 + ty + i) * C + tx0 + tx];
    __syncthreads();
    #pragma unroll
    for (int i = 0; i < 32; i += 8)
        dst[(size_t)(tx0 + ty + i) * R + ty0 + tx] = f2bf(tile[tx][ty + i]);
}

// ---------------------------------------------------------------------------
// bf16 MFMA GEMM, 128(M)x64(N), BK=32 dbuf pipeline. grid=(M/128,N/64):
// M-blocks on x -> XCD-pinned A rows. Conflict-free f(row)=(row>>1)&3
// chunk swizzle. Used for QKV, FFN1. 24 KB LDS -> 6 blocks/CU (24 waves/CU:
// the R15 lesson -- never trade waves/CU for synchronization freedom).
// ---------------------------------------------------------------------------
__global__ __launch_bounds__(256) void mm64_kernel(const short* __restrict__ A,
        const short* __restrict__ Bt, void* __restrict__ C,
        const float* __restrict__ bias, const float* __restrict__ resid,
        int M, int N, int K, int relu, int out_bf16)
{
    __shared__ short As[2][128 * 32];
    __shared__ short Bs[2][64 * 32];
    const int tid = threadIdx.x;
    const int wave = tid >> 6, lane = tid & 63;
    const int quad = lane >> 4, l15 = lane & 15;
    const int m0 = blockIdx.x * 128, n0 = blockIdx.y * 64;
    const int mw = (wave & 1) * 64, nw = (wave >> 1) * 32;

#define STAGE_M64(bufi, kk) \
    { \
        for (int r = 0; r < 2; ++r) { \
            int c = r * 256 + tid; \
            int row = c >> 2, seg = (c & 3) ^ ((row >> 1) & 3); \
            GLL16(A + (size_t)(m0 + row) * K + (kk) + seg * 8, \
                  As[bufi] + (size_t)(r * 256 + wave * 64) * 8); \
        } \
        { \
            int row = tid >> 2, seg = (tid & 3) ^ ((row >> 1) & 3); \
            GLL16(Bt + (size_t)(n0 + row) * K + (kk) + seg * 8, \
                  Bs[bufi] + (size_t)(wave * 64) * 8); \
        } \
    }

    f32x4 acc[4][2];
    #pragma unroll
    for (int i = 0; i < 4; ++i)
        #pragma unroll
        for (int j = 0; j < 2; ++j)
            acc[i][j] = (f32x4){0.f, 0.f, 0.f, 0.f};

    STAGE_M64(0, 0);
    int buf = 0;
    for (int k0 = 0; k0 < K; k0 += 32) {
        __syncthreads();
        if (k0 + 32 < K) STAGE_M64(buf ^ 1, k0 + 32);
        b16x8 af[4], bf[2];
        #pragma unroll
        for (int i = 0; i < 4; ++i) {
            int row = mw + i * 16 + l15;
            af[i] = *(const b16x8*)(As[buf] + row * 32 + ((quad ^ ((row >> 1) & 3)) * 8));
        }
        #pragma unroll
        for (int j = 0; j < 2; ++j) {
            int row = nw + j * 16 + l15;
            bf[j] = *(const b16x8*)(Bs[buf] + row * 32 + ((quad ^ ((row >> 1) & 3)) * 8));
        }
        #pragma unroll
        for (int i = 0; i < 4; ++i)
            #pragma unroll
            for (int j = 0; j < 2; ++j)
                acc[i][j] = MFMA16(af[i], bf[j], acc[i][j]);
        buf ^= 1;
    }
#undef STAGE_M64

    #pragma unroll
    for (int i = 0; i < 4; ++i) {
        #pragma unroll
        for (int r = 0; r < 4; ++r) {
            size_t row = (size_t)(m0 + mw + i * 16 + quad * 4 + r);
            #pragma unroll
            for (int j = 0; j < 2; ++j) {
                int col = n0 + nw + j * 16 + l15;
                float v = acc[i][j][r];
                if (bias)  v += bias[col];
                if (resid) v += resid[row * N + col];
                if (relu)  v = fmaxf(v, 0.0f);
                if (out_bf16) ((short*)C)[row * N + col] = f2bf(v);
                else          ((float*)C)[row * N + col] = v;
            }
        }
    }
}

// ---------------------------------------------------------------------------
// bf16 MFMA GEMM, 64x64, BK=64 dbuf pipeline (proj, FFN2). grid=(M/64, N/64)
// = 1024 blocks. BK=64 halves the serial barrier-iteration count; LDS 32 KB
// keeps 4 blocks/CU. Chunk swizzle f(row)=row&7 (R6-verified conflict-free).
// ---------------------------------------------------------------------------
__global__ __launch_bounds__(256) void mm6464_kernel(const short* __restrict__ A,
        const short* __restrict__ Bt, void* __restrict__ C,
        const float* __restrict__ bias, const float* __restrict__ resid,
        int M, int N, int K, int relu, int out_bf16)
{
    __shared__ short As[2][64 * 64];
    __shared__ short Bs[2][64 * 64];
    const int tid = threadIdx.x;
    const int wave = tid >> 6, lane = tid & 63;
    const int quad = lane >> 4, l15 = lane & 15;
    const int m0 = blockIdx.x * 64, n0 = blockIdx.y * 64;
    const int nw = wave * 16;

#define STAGE_M66(bufi, kk) \
    { \
        for (int r = 0; r < 2; ++r) { \
            int c = r * 256 + tid; \
            int row = c >> 3, seg = (c & 7) ^ (row & 7); \
            GLL16(A + (size_t)(m0 + row) * K + (kk) + seg * 8, \
                  As[bufi] + (size_t)(r * 256 + wave * 64) * 8); \
            GLL16(Bt + (size_t)(n0 + row) * K + (kk) + seg * 8, \
                  Bs[bufi] + (size_t)(r * 256 + wave * 64) * 8); \
        } \
    }

    f32x4 acc[4];
    #pragma unroll
    for (int i = 0; i < 4; ++i) acc[i] = (f32x4){0.f, 0.f, 0.f, 0.f};

    STAGE_M66(0, 0);
    int buf = 0;
    for (int k0 = 0; k0 < K; k0 += 64) {
        __syncthreads();
        if (k0 + 64 < K) STAGE_M66(buf ^ 1, k0 + 64);
        b16x8 af[4][2], bf[2];
        #pragma unroll
        for (int i = 0; i < 4; ++i)
            #pragma unroll
            for (int kb = 0; kb < 2; ++kb) {
                int row = i * 16 + l15;
                af[i][kb] = *(const b16x8*)(As[buf] + row * 64 + (((kb * 4 + quad) ^ (row & 7)) * 8));
            }
        #pragma unroll
        for (int kb = 0; kb < 2; ++kb) {
            int row = nw + l15;
            bf[kb] = *(const b16x8*)(Bs[buf] + row * 64 + (((kb * 4 + quad) ^ (row & 7)) * 8));
        }
        #pragma unroll
        for (int kb = 0; kb < 2; ++kb)
            #pragma unroll
            for (int i = 0; i < 4; ++i)
                acc[i] = MFMA16(af[i][kb], bf[kb], acc[i]);
        buf ^= 1;
    }
#undef STAGE_M66

    #pragma unroll
    for (int i = 0; i < 4; ++i) {
        #pragma unroll
        for (int r = 0; r < 4; ++r) {
            size_t row = (size_t)(m0 + i * 16 + quad * 4 + r);
            int col = n0 + nw + l15;
            float v = acc[i][r];
            if (bias)  v += bias[col];
            if (resid) v += resid[row * N + col];
            if (relu)  v = fmaxf(v, 0.0f);
            if (out_bf16) ((short*)C)[row * N + col] = f2bf(v);
            else          ((float*)C)[row * N + col] = v;
        }
    }
}

// ---------------------------------------------------------------------------
// Flash attention, S^T formulation, SPLIT-K x2, STATIC-MAX softmax (m == 0):
// LN-normalized inputs bound |S*SC2| << fp32 exp2 range, so no running max,
// no alpha rescale, and the split combine is pure l-weighting.
// grid (32 bh, 32 qt, 2 split). 25.6 KB LDS, 6 blocks/CU.
// ---------------------------------------------------------------------------
__global__ __launch_bounds__(256) void attn_kernel(const short* __restrict__ qkv,
        short* __restrict__ Opart, float* __restrict__ Ml)
{
    __shared__ short Qs[64 * 72];   // [0..64*64): swizzled Q; epilogue: stride-72 repack
    __shared__ short Ks[64 * 64];   // [tok][dh], swizzled
    __shared__ short Vt[64 * 64];   // [dh][tok], granule-swizzled, stride 64

    const int tid = threadIdx.x;
    const int wave = tid >> 6, lane = tid & 63;
    const int quad = lane >> 4, l15 = lane & 15;
    const int bh = blockIdx.x;
    const int qi = 31 - (int)blockIdx.y;
    const int split = blockIdx.z;
    const int b = bh >> 3, h = bh & 7;
    const size_t tok0 = (size_t)b * T_;
    const int qrow_rel = wave * 16 + l15;
    const int half = (qi + 1) >> 1;
    const int klo = split ? half : 0;
    const int khi = split ? qi + 1 : half;
    const int pidx = split * 1024 + bh * 32 + qi;
    short* Op = Opart + (size_t)pidx * 4096;
    float* mlp = Ml + (size_t)pidx * 64;

    if (klo >= khi) {               // empty split (qi==0, split==0)
        for (int i = tid; i < 2048; i += 256) ((int*)Op)[i] = 0;
        if (tid < 64) mlp[tid] = 0.0f;
        return;
    }

    // stage Q tile (swizzled)
    #pragma unroll
    for (int r = 0; r < 2; ++r) {
        int c = r * 256 + tid;
        int tk = c >> 3;
        int seg = (c & 7) ^ (tk & 7);
        GLL16(qkv + (tok0 + qi * 64 + tk) * 1536 + h * 64 + seg * 8,
              Qs + (size_t)(r * 256 + wave * 64) * 8);
    }

    float lrow = 0.0f;
    f32x4 ot[4];   // O^T: row=dh=dt*16+quad*4+rr, col=qrow=l15
    #pragma unroll
    for (int dt = 0; dt < 4; ++dt) ot[dt] = (f32x4){0.f, 0.f, 0.f, 0.f};

    b16x8 qf[2];

    for (int kj = klo; kj < khi; ++kj) {
        __syncthreads();   // prev-iter LDS reads done (and Q GLL drained on first)
        // stage K tile (swizzled)
        #pragma unroll
        for (int r = 0; r < 2; ++r) {
            int c = r * 256 + tid;
            int tk = c >> 3;
            int seg = (c & 7) ^ (tk & 7);
            GLL16(qkv + (tok0 + kj * 64 + tk) * 1536 + 512 + h * 64 + seg * 8,
                  Ks + (size_t)(r * 256 + wave * 64) * 8);
        }
        // stage V transposed, granule-swizzled: thread = (s 0..7, tp 0..31)
        {
            int s = tid >> 5, tp = tid & 31;
            const short* g0 = qkv + (tok0 + kj * 64 + tp * 2) * 1536 + 1024 + h * 64 + s * 8;
            b16x8 v0 = *(const b16x8*)g0;
            b16x8 v1 = *(const b16x8*)(g0 + 1536);
            int* vo = (int*)Vt;
            int gg = tp >> 1, hlf = tp & 1;
            #pragma unroll
            for (int e = 0; e < 8; ++e) {
                int row = s * 8 + e;
                unsigned int pk = (unsigned int)(unsigned short)v0[e]
                                | ((unsigned int)(unsigned short)v1[e] << 16);
                vo[row * 32 + ((gg ^ (row & 15)) << 1) + hlf] = pk;
            }
        }
        __syncthreads();

        if (kj == klo) {   // Q fragment (B-operand: n=l15=qrow, k=quad*8+j), hoisted
            #pragma unroll
            for (int kb = 0; kb < 2; ++kb) {
                int row = wave * 16 + l15;
                qf[kb] = *(const b16x8*)(Qs + row * 64 + (((kb * 4 + quad) ^ (row & 7)) * 8));
            }
        }

        // S^T = K Q^T  (A=K-frag, B=Q-frag)
        f32x4 st[4];   // mt token-tiles: token = mt*16+quad*4+r, qrow = l15
        #pragma unroll
        for (int mt = 0; mt < 4; ++mt) st[mt] = (f32x4){0.f, 0.f, 0.f, 0.f};
        #pragma unroll
        for (int mt = 0; mt < 4; ++mt) {
            int trow = mt * 16 + l15;
            #pragma unroll
            for (int kb = 0; kb < 2; ++kb) {
                b16x8 kf = *(const b16x8*)(Ks + trow * 64 + (((kb * 4 + quad) ^ (trow & 7)) * 8));
                st[mt] = MFMA16(kf, qf[kb], st[mt]);
            }
        }

        // causal mask + P = exp2(S*SC2) (no max subtraction)
        const bool diag = (kj == qi);
        float rs = 0.0f;
        b16x4 pf[4];   // P^T fragments: directly in 16x16x16 B-operand layout
        #pragma unroll
        for (int mt = 0; mt < 4; ++mt)
            #pragma unroll
            for (int r = 0; r < 4; ++r) {
                float s = st[mt][r];
                if (diag && (mt * 16 + quad * 4 + r) > qrow_rel) s = NEGINF_;
                float e = EXP2F(s * SC2_);
                rs += e;
                pf[mt][r] = f2bf_trunc(e);
            }
        rs += __shfl_xor(rs, 16);
        rs += __shfl_xor(rs, 32);
        lrow += rs;
        // O^T += V^T P^T  (16x16x16; A=V^T-frag from swizzled Vt, B=P^T in regs)
        #pragma unroll
        for (int dt = 0; dt < 4; ++dt) {
            const short* vrow = Vt + (dt * 16 + l15) * 64;
            #pragma unroll
            for (int kt = 0; kt < 4; ++kt) {
                b16x4 vf = *(const b16x4*)(vrow + (((kt * 4 + quad) ^ l15) << 2));
                ot[dt] = MFMA16K16(vf, pf[kt], ot[dt]);
            }
        }
    }

    // epilogue: normalize, repack via same-wave LDS strip (Qs alias), store
    __syncthreads();   // all waves done reading Ks/Vt AND Qs fragments
    float inv = 1.0f / lrow;
    #pragma unroll
    for (int dt = 0; dt < 4; ++dt) {
        b16x4 o4;
        o4[0] = f2bf(ot[dt][0] * inv);
        o4[1] = f2bf(ot[dt][1] * inv);
        o4[2] = f2bf(ot[dt][2] * inv);
        o4[3] = f2bf(ot[dt][3] * inv);
        *(b16x4*)(Qs + (size_t)qrow_rel * 72 + dt * 16 + quad * 4) = o4;
    }
    // rows tid>>2 land inside this wave's own strip -> DS in-order, no barrier
    {
        int row = tid >> 2, ch = tid & 3;
        b16x8 lo = *(const b16x8*)(Qs + (size_t)row * 72 + ch * 16);
        b16x8 hi = *(const b16x8*)(Qs + (size_t)row * 72 + ch * 16 + 8);
        short* dst = Op + row * 64 + ch * 16;
        *(b16x8*)dst = lo;
        *(b16x8*)(dst + 8) = hi;
    }
    if (quad == 0) mlp[qrow_rel] = lrow;
}

// ---------------------------------------------------------------------------
// Combine the two attn split-K partials: O = (l1*O1 + l2*O2)/(l1+l2).
// grid 1024 (one (bh,qi) per block), 256 threads.
// ---------------------------------------------------------------------------
__global__ __launch_bounds__(256) void attn_combine_kernel(
        const short* __restrict__ Opart, const float* __restrict__ Ml,
        short* __restrict__ Ob)
{
    int pair = blockIdx.x;              // bh*32 + qi
    int bh = pair >> 5, qi = pair & 31;
    int b = bh >> 3, h = bh & 7;
    int tid = threadIdx.x;
    const short* O1 = Opart + (size_t)pair * 4096;
    const short* O2 = Opart + (size_t)(1024 + pair) * 4096;
    const float* ml1 = Ml + (size_t)pair * 64;
    const float* ml2 = Ml + (size_t)(1024 + pair) * 64;
    int ch = tid & 7;                   // 8 shorts per chunk
    #pragma unroll
    for (int it = 0; it < 2; ++it) {
        int row = it * 32 + (tid >> 3);
        float l1 = ml1[row], l2 = ml2[row];
        float inv = 1.0f / (l1 + l2);
        float w1 = l1 * inv, w2 = l2 * inv;
        b16x8 a = *(const b16x8*)(O1 + row * 64 + ch * 8);
        b16x8 c = *(const b16x8*)(O2 + row * 64 + ch * 8);
        b16x8 o;
        #pragma unroll
        for (int e = 0; e < 8; ++e)
            o[e] = f2bf(w1 * bf2f(a[e]) + w2 * bf2f(c[e]));
        short* dst = Ob + ((size_t)(b * T_ + qi * 64 + row)) * 512 + h * 64 + ch * 8;
        *(b16x8*)dst = o;
    }
}

// ---------------------------------------------------------------------------
extern "C" void kernel_launch(void* const* d_in, const int* in_sizes, int n_in,
                              void* d_out, int out_size, void* d_ws, size_t ws_size,
                              hipStream_t stream) {
    (void)in_sizes; (void)n_in; (void)out_size; (void)ws_size;
    const float* x     = (const float*)d_in[0];
    const float* ln_g  = (const float*)d_in[1];
    const float* ln_b  = (const float*)d_in[2];
    const float* Wq    = (const float*)d_in[3];
    const float* Wk    = (const float*)d_in[4];
    const float* Wv    = (const float*)d_in[5];
    const float* Wproj = (const float*)d_in[6];
    const float* bproj = (const float*)d_in[7];
    const float* W1    = (const float*)d_in[8];
    const float* b1    = (const float*)d_in[9];
    const float* W2    = (const float*)d_in[10];
    const float* b2    = (const float*)d_in[11];
    float* out = (float*)d_out;

    char* W = (char*)d_ws;
    short* hbuf  = (short*)(W + 0);                    // 8 MB  (LN out, bf16)
    short* qkvb  = (short*)(W + ((size_t)8  << 20));   // 24 MB [BT][1536]
    short* attno = (short*)(W + ((size_t)32 << 20));   // 8 MB  [BT][512]
    float* x1    = (float*)(W + ((size_t)40 << 20));   // 16 MB
    short* ff1   = (short*)(W + ((size_t)56 << 20));   // 32 MB [BT][2048]
    short* wqkv  = (short*)(W + ((size_t)88 << 20));   // 1.5 MB [1536][512]
    short* wpt   = (short*)(W + ((size_t)90 << 20));   // 0.5 MB [512][512]
    short* w1t   = (short*)(W + ((size_t)91 << 20));   // 2 MB  [2048][512]
    short* w2t   = (short*)(W + ((size_t)93 << 20));   // 2 MB  [512][2048]
    short* Opart = (short*)(W + ((size_t)96 << 20));   // 16 MB [2][1024][64][64] bf16
    float* Ml    = (float*)(W + ((size_t)112 << 20));  // 0.5 MB [2][1024][64] fp32

    // 0. all weight transposes in one launch
    prep_kernel<<<dim3(3072), dim3(32, 8), 0, stream>>>(
        Wq, Wk, Wv, Wproj, W1, W2, wqkv, wpt, w1t, w2t);
    // 1. h = LN(x) -> bf16
    ln_kernel<<<dim3(BT_ / 4), dim3(256), 0, stream>>>(x, ln_g, ln_b, hbuf);
    // 2. qkv = h @ Wqkv  [8192,1536] bf16  (128x64 tiles -> 1536 blocks, 6/CU)
    mm64_kernel<<<dim3(64, 24), dim3(256), 0, stream>>>(hbuf, wqkv, qkvb,
        nullptr, nullptr, BT_, 1536, D_, 0, 1);
    // 3. attention split-K x2 -> partials, then combine -> attno bf16
    attn_kernel<<<dim3(32, 32, 2), dim3(256), 0, stream>>>(qkvb, Opart, Ml);
    attn_combine_kernel<<<dim3(1024), dim3(256), 0, stream>>>(Opart, Ml, attno);
    // 4. x1 = x + attno @ Wproj + bproj  (fp32, BK=64 -> 16 iters)
    mm6464_kernel<<<dim3(128, 8), dim3(256), 0, stream>>>(attno, wpt, x1,
        bproj, x, BT_, D_, D_, 0, 0);
    // 5. h2 = LN(x1) -> bf16 (reuse hbuf)
    ln_kernel<<<dim3(BT_ / 4), dim3(256), 0, stream>>>(x1, ln_g, ln_b, hbuf);
    // 6. ff1 = relu(h2 @ W1 + b1)  bf16  (128x64 tiles -> 2048 blocks)
    mm64_kernel<<<dim3(64, 32), dim3(256), 0, stream>>>(hbuf, w1t, ff1,
        b1, nullptr, BT_, FF_, D_, 1, 1);
    // 7. out = x1 + ff1 @ W2 + b2  (fp32, BK=64 -> 32 iters, fused epilogue)
    mm6464_kernel<<<dim3(128, 8), dim3(256), 0, stream>>>(ff1, w2t, out,
        b2, x1, BT_, D_, FF_, 0, 0);
}

// Round 17
// 254.367 us; speedup vs baseline: 1.2607x; 1.0176x over previous
//
#include <hip/hip_runtime.h>
#include <math.h>

#define B_ 4
#define T_ 2048
#define D_ 512
#define H_ 8
#define DH_ 64
#define BT_ 8192
#define FF_ 2048
#define EPS_ 1e-5f
#define SCALE_ 0.04419417382415922f   // 512^-0.5
#define SC2_ 0.06375861151f           // SCALE_ * log2(e)
#define NEGINF_ -1e30f

typedef short b16x8 __attribute__((ext_vector_type(8)));
typedef short b16x4 __attribute__((ext_vector_type(4)));
typedef float f32x4 __attribute__((ext_vector_type(4)));

#define MFMA16(a, b, c) __builtin_amdgcn_mfma_f32_16x16x32_bf16(a, b, c, 0, 0, 0)
#define MFMA16K16(a, b, c) __builtin_amdgcn_mfma_f32_16x16x16bf16_1k(a, b, c, 0, 0, 0)

#define GLL16(gp, lp) \
    __builtin_amdgcn_global_load_lds((const __attribute__((address_space(1))) void*)(gp), \
                                     (__attribute__((address_space(3))) void*)(lp), 16, 0, 0)

#if __has_builtin(__builtin_amdgcn_exp2f)
#define EXP2F(x) __builtin_amdgcn_exp2f(x)
#else
#define EXP2F(x) exp2f(x)
#endif

// fp32 -> bf16 RNE (finite inputs)
static __device__ inline short f2bf(float f) {
    unsigned int u = __builtin_bit_cast(unsigned int, f);
    unsigned int r = (u + 0x7fffu + ((u >> 16) & 1u)) >> 16;
    return (short)r;
}
// fp32 -> bf16 truncation (1 VALU op; used for P where bias is negligible)
static __device__ inline short f2bf_trunc(float f) {
    return (short)(__builtin_bit_cast(unsigned int, f) >> 16);
}
// bf16 -> fp32
static __device__ inline float bf2f(short s) {
    return __builtin_bit_cast(float, ((unsigned int)(unsigned short)s) << 16);
}

// ---------------------------------------------------------------------------
// Prologue: weight transposes (blocks 0..3071) + LN1 of x (blocks 3072..5119).
// Merging the two independent preprocessing kernels removes one launch gap.
// block (32,8) = 256 threads.
// ---------------------------------------------------------------------------
__global__ __launch_bounds__(256) void prologue_kernel(
        const float* __restrict__ Wq, const float* __restrict__ Wk,
        const float* __restrict__ Wv, const float* __restrict__ Wp,
        const float* __restrict__ W1, const float* __restrict__ W2,
        short* __restrict__ wqkv, short* __restrict__ wpt,
        short* __restrict__ w1t, short* __restrict__ w2t,
        const float* __restrict__ X, const float* __restrict__ G,
        const float* __restrict__ Bb, short* __restrict__ Y)
{
    __shared__ float tile[32][33];
    int idx = blockIdx.x;
    if (idx >= 3072) {
        // LayerNorm: 4 rows/block, one row per wave
        int tid = threadIdx.y * 32 + threadIdx.x;
        int wave = tid >> 6, t = tid & 63;
        int row = (idx - 3072) * 4 + wave;
        const float* xr = X + (size_t)row * D_;
        float4 v0 = *(const float4*)(xr + t * 4);
        float4 v1 = *(const float4*)(xr + 256 + t * 4);
        float sum = v0.x + v0.y + v0.z + v0.w + v1.x + v1.y + v1.z + v1.w;
        float ssq = v0.x*v0.x + v0.y*v0.y + v0.z*v0.z + v0.w*v0.w
                  + v1.x*v1.x + v1.y*v1.y + v1.z*v1.z + v1.w*v1.w;
        #pragma unroll
        for (int off = 32; off > 0; off >>= 1) {
            sum += __shfl_down(sum, off);
            ssq += __shfl_down(ssq, off);
        }
        sum = __shfl(sum, 0);
        ssq = __shfl(ssq, 0);
        float mean = sum * (1.0f / D_);
        float var  = ssq * (1.0f / D_) - mean * mean;
        float rstd = rsqrtf(var + EPS_);
        float4 g0 = *(const float4*)(G + t * 4);
        float4 g1 = *(const float4*)(G + 256 + t * 4);
        float4 b0 = *(const float4*)(Bb + t * 4);
        float4 b1 = *(const float4*)(Bb + 256 + t * 4);
        short4 o0, o1;
        o0.x = f2bf((v0.x - mean) * rstd * g0.x + b0.x);
        o0.y = f2bf((v0.y - mean) * rstd * g0.y + b0.y);
        o0.z = f2bf((v0.z - mean) * rstd * g0.z + b0.z);
        o0.w = f2bf((v0.w - mean) * rstd * g0.w + b0.w);
        o1.x = f2bf((v1.x - mean) * rstd * g1.x + b1.x);
        o1.y = f2bf((v1.y - mean) * rstd * g1.y + b1.y);
        o1.z = f2bf((v1.z - mean) * rstd * g1.z + b1.z);
        o1.w = f2bf((v1.w - mean) * rstd * g1.w + b1.w);
        short* yr = Y + (size_t)row * D_;
        *(short4*)(yr + t * 4)       = o0;
        *(short4*)(yr + 256 + t * 4) = o1;
        return;
    }
    const float* src; short* dst; int R, C, tx0, ty0;
    if (idx < 768) {            // Wq/Wk/Wv: per head [512][64] -> [64][512]
        int w = idx >> 8, rem = idx & 255;
        int hh = rem >> 5, t = rem & 31;
        const float* base = (w == 0) ? Wq : ((w == 1) ? Wk : Wv);
        src = base + hh * (D_ * DH_);
        dst = wqkv + w * (512 * 512) + hh * (DH_ * D_);
        R = 512; C = 64; tx0 = (t & 1) * 32; ty0 = (t >> 1) * 32;
    } else if (idx < 1024) {    // Wproj [512][512]
        int t = idx - 768;
        src = Wp; dst = wpt; R = 512; C = 512;
        tx0 = (t & 15) * 32; ty0 = (t >> 4) * 32;
    } else if (idx < 2048) {    // W1 [512][2048] -> [2048][512]
        int t = idx - 1024;
        src = W1; dst = w1t; R = 512; C = 2048;
        tx0 = (t & 63) * 32; ty0 = (t >> 6) * 32;
    } else {                    // W2 [2048][512] -> [512][2048]
        int t = idx - 2048;
        src = W2; dst = w2t; R = 2048; C = 512;
        tx0 = (t & 15) * 32; ty0 = (t >> 4) * 32;
    }
    int tx = threadIdx.x, ty = threadIdx.y;
    #pragma unroll
    for (int i = 0; i < 32; i += 8)
        tile[ty + i][tx] = src[(size_t)(ty0 + ty + i) * C + tx0 + tx];
    __syncthreads();
    #pragma unroll
    for (int i = 0; i < 32; i += 8)
        dst[(size_t)(tx0 + ty + i) * R + ty0 + tx] = f2bf(tile[tx][ty + i]);
}

// ---------------------------------------------------------------------------
// LayerNorm over bf16 input (x1 path): 4 rows/block, one row per wave.
// Each lane handles 8 contiguous elements (one b16x8).
// ---------------------------------------------------------------------------
__global__ __launch_bounds__(256) void ln_bf16_kernel(const short* __restrict__ X,
        const float* __restrict__ G, const float* __restrict__ Bb,
        short* __restrict__ Y)
{
    int wave = threadIdx.x >> 6, t = threadIdx.x & 63;
    int row = blockIdx.x * 4 + wave;
    const short* xr = X + (size_t)row * D_ + t * 8;
    b16x8 xv = *(const b16x8*)xr;
    float v[8];
    float sum = 0.0f, ssq = 0.0f;
    #pragma unroll
    for (int e = 0; e < 8; ++e) {
        v[e] = bf2f(xv[e]);
        sum += v[e];
        ssq += v[e] * v[e];
    }
    #pragma unroll
    for (int off = 32; off > 0; off >>= 1) {
        sum += __shfl_down(sum, off);
        ssq += __shfl_down(ssq, off);
    }
    sum = __shfl(sum, 0);
    ssq = __shfl(ssq, 0);
    float mean = sum * (1.0f / D_);
    float var  = ssq * (1.0f / D_) - mean * mean;
    float rstd = rsqrtf(var + EPS_);

    float4 g0 = *(const float4*)(G + t * 8);
    float4 g1 = *(const float4*)(G + t * 8 + 4);
    float4 b0 = *(const float4*)(Bb + t * 8);
    float4 b1 = *(const float4*)(Bb + t * 8 + 4);
    float gg[8] = {g0.x, g0.y, g0.z, g0.w, g1.x, g1.y, g1.z, g1.w};
    float bb[8] = {b0.x, b0.y, b0.z, b0.w, b1.x, b1.y, b1.z, b1.w};
    b16x8 o;
    #pragma unroll
    for (int e = 0; e < 8; ++e)
        o[e] = f2bf((v[e] - mean) * rstd * gg[e] + bb[e]);
    *(b16x8*)(Y + (size_t)row * D_ + t * 8) = o;
}

// ---------------------------------------------------------------------------
// bf16 MFMA GEMM, 128(M)x64(N), BK=32 dbuf pipeline. grid=(M/128,N/64):
// M-blocks on x -> XCD-pinned A rows. Conflict-free f(row)=(row>>1)&3
// chunk swizzle. Used for QKV, FFN1. 24 KB LDS -> 6 blocks/CU.
// ---------------------------------------------------------------------------
__global__ __launch_bounds__(256) void mm64_kernel(const short* __restrict__ A,
        const short* __restrict__ Bt, void* __restrict__ C,
        const float* __restrict__ bias, const float* __restrict__ resid,
        int M, int N, int K, int relu, int out_bf16)
{
    __shared__ short As[2][128 * 32];
    __shared__ short Bs[2][64 * 32];
    const int tid = threadIdx.x;
    const int wave = tid >> 6, lane = tid & 63;
    const int quad = lane >> 4, l15 = lane & 15;
    const int m0 = blockIdx.x * 128, n0 = blockIdx.y * 64;
    const int mw = (wave & 1) * 64, nw = (wave >> 1) * 32;

#define STAGE_M64(bufi, kk) \
    { \
        for (int r = 0; r < 2; ++r) { \
            int c = r * 256 + tid; \
            int row = c >> 2, seg = (c & 3) ^ ((row >> 1) & 3); \
            GLL16(A + (size_t)(m0 + row) * K + (kk) + seg * 8, \
                  As[bufi] + (size_t)(r * 256 + wave * 64) * 8); \
        } \
        { \
            int row = tid >> 2, seg = (tid & 3) ^ ((row >> 1) & 3); \
            GLL16(Bt + (size_t)(n0 + row) * K + (kk) + seg * 8, \
                  Bs[bufi] + (size_t)(wave * 64) * 8); \
        } \
    }

    f32x4 acc[4][2];
    #pragma unroll
    for (int i = 0; i < 4; ++i)
        #pragma unroll
        for (int j = 0; j < 2; ++j)
            acc[i][j] = (f32x4){0.f, 0.f, 0.f, 0.f};

    STAGE_M64(0, 0);
    int buf = 0;
    for (int k0 = 0; k0 < K; k0 += 32) {
        __syncthreads();
        if (k0 + 32 < K) STAGE_M64(buf ^ 1, k0 + 32);
        b16x8 af[4], bf[2];
        #pragma unroll
        for (int i = 0; i < 4; ++i) {
            int row = mw + i * 16 + l15;
            af[i] = *(const b16x8*)(As[buf] + row * 32 + ((quad ^ ((row >> 1) & 3)) * 8));
        }
        #pragma unroll
        for (int j = 0; j < 2; ++j) {
            int row = nw + j * 16 + l15;
            bf[j] = *(const b16x8*)(Bs[buf] + row * 32 + ((quad ^ ((row >> 1) & 3)) * 8));
        }
        #pragma unroll
        for (int i = 0; i < 4; ++i)
            #pragma unroll
            for (int j = 0; j < 2; ++j)
                acc[i][j] = MFMA16(af[i], bf[j], acc[i][j]);
        buf ^= 1;
    }
#undef STAGE_M64

    #pragma unroll
    for (int i = 0; i < 4; ++i) {
        #pragma unroll
        for (int r = 0; r < 4; ++r) {
            size_t row = (size_t)(m0 + mw + i * 16 + quad * 4 + r);
            #pragma unroll
            for (int j = 0; j < 2; ++j) {
                int col = n0 + nw + j * 16 + l15;
                float v = acc[i][j][r];
                if (bias)  v += bias[col];
                if (resid) v += resid[row * N + col];
                if (relu)  v = fmaxf(v, 0.0f);
                if (out_bf16) ((short*)C)[row * N + col] = f2bf(v);
                else          ((float*)C)[row * N + col] = v;
            }
        }
    }
}

// ---------------------------------------------------------------------------
// bf16 MFMA GEMM, 64x64, BK=64 dbuf pipeline (proj, FFN2). grid=(M/64, N/64).
// BK=64 halves the serial barrier-iteration count; 32 KB LDS keeps 4 blk/CU.
// Chunk swizzle f(row)=row&7 (R6-verified conflict-free). resid may be fp32
// or bf16 (resid_bf16 flag) -- the x1 residual path is bf16 to cut HBM.
// ---------------------------------------------------------------------------
__global__ __launch_bounds__(256) void mm6464_kernel(const short* __restrict__ A,
        const short* __restrict__ Bt, void* __restrict__ C,
        const float* __restrict__ bias, const void* __restrict__ resid,
        int M, int N, int K, int relu, int out_bf16, int resid_bf16)
{
    __shared__ short As[2][64 * 64];
    __shared__ short Bs[2][64 * 64];
    const int tid = threadIdx.x;
    const int wave = tid >> 6, lane = tid & 63;
    const int quad = lane >> 4, l15 = lane & 15;
    const int m0 = blockIdx.x * 64, n0 = blockIdx.y * 64;
    const int nw = wave * 16;

#define STAGE_M66(bufi, kk) \
    { \
        for (int r = 0; r < 2; ++r) { \
            int c = r * 256 + tid; \
            int row = c >> 3, seg = (c & 7) ^ (row & 7); \
            GLL16(A + (size_t)(m0 + row) * K + (kk) + seg * 8, \
                  As[bufi] + (size_t)(r * 256 + wave * 64) * 8); \
            GLL16(Bt + (size_t)(n0 + row) * K + (kk) + seg * 8, \
                  Bs[bufi] + (size_t)(r * 256 + wave * 64) * 8); \
        } \
    }

    f32x4 acc[4];
    #pragma unroll
    for (int i = 0; i < 4; ++i) acc[i] = (f32x4){0.f, 0.f, 0.f, 0.f};

    STAGE_M66(0, 0);
    int buf = 0;
    for (int k0 = 0; k0 < K; k0 += 64) {
        __syncthreads();
        if (k0 + 64 < K) STAGE_M66(buf ^ 1, k0 + 64);
        b16x8 af[4][2], bf[2];
        #pragma unroll
        for (int i = 0; i < 4; ++i)
            #pragma unroll
            for (int kb = 0; kb < 2; ++kb) {
                int row = i * 16 + l15;
                af[i][kb] = *(const b16x8*)(As[buf] + row * 64 + (((kb * 4 + quad) ^ (row & 7)) * 8));
            }
        #pragma unroll
        for (int kb = 0; kb < 2; ++kb) {
            int row = nw + l15;
            bf[kb] = *(const b16x8*)(Bs[buf] + row * 64 + (((kb * 4 + quad) ^ (row & 7)) * 8));
        }
        #pragma unroll
        for (int kb = 0; kb < 2; ++kb)
            #pragma unroll
            for (int i = 0; i < 4; ++i)
                acc[i] = MFMA16(af[i][kb], bf[kb], acc[i]);
        buf ^= 1;
    }
#undef STAGE_M66

    #pragma unroll
    for (int i = 0; i < 4; ++i) {
        #pragma unroll
        for (int r = 0; r < 4; ++r) {
            size_t row = (size_t)(m0 + i * 16 + quad * 4 + r);
            int col = n0 + nw + l15;
            float v = acc[i][r];
            if (bias)  v += bias[col];
            if (resid) {
                if (resid_bf16) v += bf2f(((const short*)resid)[row * N + col]);
                else            v += ((const float*)resid)[row * N + col];
            }
            if (relu)  v = fmaxf(v, 0.0f);
            if (out_bf16) ((short*)C)[row * N + col] = f2bf(v);
            else          ((float*)C)[row * N + col] = v;
        }
    }
}

// ---------------------------------------------------------------------------
// Flash attention, S^T formulation, SPLIT-K x2, STATIC-MAX softmax (m == 0).
// grid (32 bh, 32 qt, 2 split). 25.6 KB LDS, 6 blocks/CU.
// ---------------------------------------------------------------------------
__global__ __launch_bounds__(256) void attn_kernel(const short* __restrict__ qkv,
        short* __restrict__ Opart, float* __restrict__ Ml)
{
    __shared__ short Qs[64 * 72];   // [0..64*64): swizzled Q; epilogue: stride-72 repack
    __shared__ short Ks[64 * 64];   // [tok][dh], swizzled
    __shared__ short Vt[64 * 64];   // [dh][tok], granule-swizzled, stride 64

    const int tid = threadIdx.x;
    const int wave = tid >> 6, lane = tid & 63;
    const int quad = lane >> 4, l15 = lane & 15;
    const int bh = blockIdx.x;
    const int qi = 31 - (int)blockIdx.y;
    const int split = blockIdx.z;
    const int b = bh >> 3, h = bh & 7;
    const size_t tok0 = (size_t)b * T_;
    const int qrow_rel = wave * 16 + l15;
    const int half = (qi + 1) >> 1;
    const int klo = split ? half : 0;
    const int khi = split ? qi + 1 : half;
    const int pidx = split * 1024 + bh * 32 + qi;
    short* Op = Opart + (size_t)pidx * 4096;
    float* mlp = Ml + (size_t)pidx * 64;

    if (klo >= khi) {               // empty split (qi==0, split==0)
        for (int i = tid; i < 2048; i += 256) ((int*)Op)[i] = 0;
        if (tid < 64) mlp[tid] = 0.0f;
        return;
    }

    // stage Q tile (swizzled)
    #pragma unroll
    for (int r = 0; r < 2; ++r) {
        int c = r * 256 + tid;
        int tk = c >> 3;
        int seg = (c & 7) ^ (tk & 7);
        GLL16(qkv + (tok0 + qi * 64 + tk) * 1536 + h * 64 + seg * 8,
              Qs + (size_t)(r * 256 + wave * 64) * 8);
    }

    float lrow = 0.0f;
    f32x4 ot[4];   // O^T: row=dh=dt*16+quad*4+rr, col=qrow=l15
    #pragma unroll
    for (int dt = 0; dt < 4; ++dt) ot[dt] = (f32x4){0.f, 0.f, 0.f, 0.f};

    b16x8 qf[2];

    for (int kj = klo; kj < khi; ++kj) {
        __syncthreads();   // prev-iter LDS reads done (and Q GLL drained on first)
        // stage K tile (swizzled)
        #pragma unroll
        for (int r = 0; r < 2; ++r) {
            int c = r * 256 + tid;
            int tk = c >> 3;
            int seg = (c & 7) ^ (tk & 7);
            GLL16(qkv + (tok0 + kj * 64 + tk) * 1536 + 512 + h * 64 + seg * 8,
                  Ks + (size_t)(r * 256 + wave * 64) * 8);
        }
        // stage V transposed, granule-swizzled: thread = (s 0..7, tp 0..31)
        {
            int s = tid >> 5, tp = tid & 31;
            const short* g0 = qkv + (tok0 + kj * 64 + tp * 2) * 1536 + 1024 + h * 64 + s * 8;
            b16x8 v0 = *(const b16x8*)g0;
            b16x8 v1 = *(const b16x8*)(g0 + 1536);
            int* vo = (int*)Vt;
            int gg = tp >> 1, hlf = tp & 1;
            #pragma unroll
            for (int e = 0; e < 8; ++e) {
                int row = s * 8 + e;
                unsigned int pk = (unsigned int)(unsigned short)v0[e]
                                | ((unsigned int)(unsigned short)v1[e] << 16);
                vo[row * 32 + ((gg ^ (row & 15)) << 1) + hlf] = pk;
            }
        }
        __syncthreads();

        if (kj == klo) {   // Q fragment (B-operand: n=l15=qrow, k=quad*8+j), hoisted
            #pragma unroll
            for (int kb = 0; kb < 2; ++kb) {
                int row = wave * 16 + l15;
                qf[kb] = *(const b16x8*)(Qs + row * 64 + (((kb * 4 + quad) ^ (row & 7)) * 8));
            }
        }

        // S^T = K Q^T  (A=K-frag, B=Q-frag)
        f32x4 st[4];   // mt token-tiles: token = mt*16+quad*4+r, qrow = l15
        #pragma unroll
        for (int mt = 0; mt < 4; ++mt) st[mt] = (f32x4){0.f, 0.f, 0.f, 0.f};
        #pragma unroll
        for (int mt = 0; mt < 4; ++mt) {
            int trow = mt * 16 + l15;
            #pragma unroll
            for (int kb = 0; kb < 2; ++kb) {
                b16x8 kf = *(const b16x8*)(Ks + trow * 64 + (((kb * 4 + quad) ^ (trow & 7)) * 8));
                st[mt] = MFMA16(kf, qf[kb], st[mt]);
            }
        }

        // causal mask + P = exp2(S*SC2) (no max subtraction)
        const bool diag = (kj == qi);
        float rs = 0.0f;
        b16x4 pf[4];   // P^T fragments: directly in 16x16x16 B-operand layout
        #pragma unroll
        for (int mt = 0; mt < 4; ++mt)
            #pragma unroll
            for (int r = 0; r < 4; ++r) {
                float s = st[mt][r];
                if (diag && (mt * 16 + quad * 4 + r) > qrow_rel) s = NEGINF_;
                float e = EXP2F(s * SC2_);
                rs += e;
                pf[mt][r] = f2bf_trunc(e);
            }
        rs += __shfl_xor(rs, 16);
        rs += __shfl_xor(rs, 32);
        lrow += rs;
        // O^T += V^T P^T  (16x16x16; A=V^T-frag from swizzled Vt, B=P^T in regs)
        #pragma unroll
        for (int dt = 0; dt < 4; ++dt) {
            const short* vrow = Vt + (dt * 16 + l15) * 64;
            #pragma unroll
            for (int kt = 0; kt < 4; ++kt) {
                b16x4 vf = *(const b16x4*)(vrow + (((kt * 4 + quad) ^ l15) << 2));
                ot[dt] = MFMA16K16(vf, pf[kt], ot[dt]);
            }
        }
    }

    // epilogue: normalize, repack via same-wave LDS strip (Qs alias), store
    __syncthreads();   // all waves done reading Ks/Vt AND Qs fragments
    float inv = 1.0f / lrow;
    #pragma unroll
    for (int dt = 0; dt < 4; ++dt) {
        b16x4 o4;
        o4[0] = f2bf(ot[dt][0] * inv);
        o4[1] = f2bf(ot[dt][1] * inv);
        o4[2] = f2bf(ot[dt][2] * inv);
        o4[3] = f2bf(ot[dt][3] * inv);
        *(b16x4*)(Qs + (size_t)qrow_rel * 72 + dt * 16 + quad * 4) = o4;
    }
    // rows tid>>2 land inside this wave's own strip -> DS in-order, no barrier
    {
        int row = tid >> 2, ch = tid & 3;
        b16x8 lo = *(const b16x8*)(Qs + (size_t)row * 72 + ch * 16);
        b16x8 hi = *(const b16x8*)(Qs + (size_t)row * 72 + ch * 16 + 8);
        short* dst = Op + row * 64 + ch * 16;
        *(b16x8*)dst = lo;
        *(b16x8*)(dst + 8) = hi;
    }
    if (quad == 0) mlp[qrow_rel] = lrow;
}

// ---------------------------------------------------------------------------
// Combine the two attn split-K partials: O = (l1*O1 + l2*O2)/(l1+l2).
// grid 1024 (one (bh,qi) per block), 256 threads.
// ---------------------------------------------------------------------------
__global__ __launch_bounds__(256) void attn_combine_kernel(
        const short* __restrict__ Opart, const float* __restrict__ Ml,
        short* __restrict__ Ob)
{
    int pair = blockIdx.x;              // bh*32 + qi
    int bh = pair >> 5, qi = pair & 31;
    int b = bh >> 3, h = bh & 7;
    int tid = threadIdx.x;
    const short* O1 = Opart + (size_t)pair * 4096;
    const short* O2 = Opart + (size_t)(1024 + pair) * 4096;
    const float* ml1 = Ml + (size_t)pair * 64;
    const float* ml2 = Ml + (size_t)(1024 + pair) * 64;
    int ch = tid & 7;                   // 8 shorts per chunk
    #pragma unroll
    for (int it = 0; it < 2; ++it) {
        int row = it * 32 + (tid >> 3);
        float l1 = ml1[row], l2 = ml2[row];
        float inv = 1.0f / (l1 + l2);
        float w1 = l1 * inv, w2 = l2 * inv;
        b16x8 a = *(const b16x8*)(O1 + row * 64 + ch * 8);
        b16x8 c = *(const b16x8*)(O2 + row * 64 + ch * 8);
        b16x8 o;
        #pragma unroll
        for (int e = 0; e < 8; ++e)
            o[e] = f2bf(w1 * bf2f(a[e]) + w2 * bf2f(c[e]));
        short* dst = Ob + ((size_t)(b * T_ + qi * 64 + row)) * 512 + h * 64 + ch * 8;
        *(b16x8*)dst = o;
    }
}

// ---------------------------------------------------------------------------
extern "C" void kernel_launch(void* const* d_in, const int* in_sizes, int n_in,
                              void* d_out, int out_size, void* d_ws, size_t ws_size,
                              hipStream_t stream) {
    (void)in_sizes; (void)n_in; (void)out_size; (void)ws_size;
    const float* x     = (const float*)d_in[0];
    const float* ln_g  = (const float*)d_in[1];
    const float* ln_b  = (const float*)d_in[2];
    const float* Wq    = (const float*)d_in[3];
    const float* Wk    = (const float*)d_in[4];
    const float* Wv    = (const float*)d_in[5];
    const float* Wproj = (const float*)d_in[6];
    const float* bproj = (const float*)d_in[7];
    const float* W1    = (const float*)d_in[8];
    const float* b1    = (const float*)d_in[9];
    const float* W2    = (const float*)d_in[10];
    const float* b2    = (const float*)d_in[11];
    float* out = (float*)d_out;

    char* W = (char*)d_ws;
    short* hbuf  = (short*)(W + 0);                    // 8 MB  (LN out, bf16)
    short* qkvb  = (short*)(W + ((size_t)8  << 20));   // 24 MB [BT][1536]
    short* attno = (short*)(W + ((size_t)32 << 20));   // 8 MB  [BT][512]
    short* x1b   = (short*)(W + ((size_t)40 << 20));   // 8 MB  [BT][512] bf16
    short* ff1   = (short*)(W + ((size_t)56 << 20));   // 32 MB [BT][2048]
    short* wqkv  = (short*)(W + ((size_t)88 << 20));   // 1.5 MB [1536][512]
    short* wpt   = (short*)(W + ((size_t)90 << 20));   // 0.5 MB [512][512]
    short* w1t   = (short*)(W + ((size_t)91 << 20));   // 2 MB  [2048][512]
    short* w2t   = (short*)(W + ((size_t)93 << 20));   // 2 MB  [512][2048]
    short* Opart = (short*)(W + ((size_t)96 << 20));   // 16 MB [2][1024][64][64] bf16
    float* Ml    = (float*)(W + ((size_t)112 << 20));  // 0.5 MB [2][1024][64] fp32

    // 0. weight transposes + LN1 fused in one launch
    prologue_kernel<<<dim3(3072 + BT_ / 4), dim3(32, 8), 0, stream>>>(
        Wq, Wk, Wv, Wproj, W1, W2, wqkv, wpt, w1t, w2t,
        x, ln_g, ln_b, hbuf);
    // 1. qkv = h @ Wqkv  [8192,1536] bf16  (128x64 tiles -> 1536 blocks, 6/CU)
    mm64_kernel<<<dim3(64, 24), dim3(256), 0, stream>>>(hbuf, wqkv, qkvb,
        nullptr, nullptr, BT_, 1536, D_, 0, 1);
    // 2. attention split-K x2 -> partials, then combine -> attno bf16
    attn_kernel<<<dim3(32, 32, 2), dim3(256), 0, stream>>>(qkvb, Opart, Ml);
    attn_combine_kernel<<<dim3(1024), dim3(256), 0, stream>>>(Opart, Ml, attno);
    // 3. x1b = bf16(x + attno @ Wproj + bproj)   (BK=64 -> 16 iters)
    mm6464_kernel<<<dim3(128, 8), dim3(256), 0, stream>>>(attno, wpt, x1b,
        bproj, x, BT_, D_, D_, 0, 1, 0);
    // 4. h2 = LN(x1b) -> bf16 (reuse hbuf)
    ln_bf16_kernel<<<dim3(BT_ / 4), dim3(256), 0, stream>>>(x1b, ln_g, ln_b, hbuf);
    // 5. ff1 = relu(h2 @ W1 + b1)  bf16  (128x64 tiles -> 2048 blocks)
    mm64_kernel<<<dim3(64, 32), dim3(256), 0, stream>>>(hbuf, w1t, ff1,
        b1, nullptr, BT_, FF_, D_, 1, 1);
    // 6. out = x1b + ff1 @ W2 + b2  (fp32 out, bf16 resid, BK=64 -> 32 iters)
    mm6464_kernel<<<dim3(128, 8), dim3(256), 0, stream>>>(ff1, w2t, out,
        b2, x1b, BT_, D_, FF_, 0, 0, 1);
}